// Round 10
// baseline (130.344 us; speedup 1.0000x reference)
//
#include <hip/hip_runtime.h>
#include <math.h>

#define NTOK 100
#define EDIM 5
#define NH   4
#define NL   3
#define DD   64
#define BLK  512

// single-instruction transcendentals (1-ulp class; tolerance is 2^-7;
// HW-validated rounds 3-9)
__device__ __forceinline__ float fexp2(float x){ float r; asm("v_exp_f32 %0, %1" : "=v"(r) : "v"(x)); return r; }
__device__ __forceinline__ float frcp (float x){ float r; asm("v_rcp_f32 %0, %1" : "=v"(r) : "v"(x)); return r; }
__device__ __forceinline__ float frsq (float x){ float r; asm("v_rsq_f32 %0, %1" : "=v"(r) : "v"(x)); return r; }

// ---------------------------------------------------------------------------
// SINGLE fused kernel (round 10): the separate precompute_mp launch + graph
// gap was the last untested serialized cost (~3-6 us).  Each block now
// computes the 24 folded 5x5 matrices redundantly during setup:
//   M[l][h] = (1/8)*log2(e) * Wq^T Wk     (softmax uses native v_exp_f32)
//   P[l][h] = Wv^T Wo_h^T
// 600 entries / 512 threads, 64-MAC dots from global (60 KB of weights,
// L2-hot after the first blocks), written straight into LDS s_MP4 --
// overlapped with the existing setup phase, before the barrier that was
// already there.  Everything else = r8's best structure: 512 thr, 1
// row/thread, j-split 2, LDS-broadcast j-loop unroll 8, lean math,
// (512,4) VGPR cap 128 (r9 proved (512,8) buys nothing).
// ---------------------------------------------------------------------------
__global__ __launch_bounds__(BLK, 4) void encoder_kernel(
    const float* __restrict__ x,
    const float* __restrict__ Wq,
    const float* __restrict__ Wk,
    const float* __restrict__ Wv,
    const float* __restrict__ Wo,
    const float* __restrict__ Wf,
    const float* __restrict__ bfv,
    const float* __restrict__ g1,
    const float* __restrict__ b1,
    const float* __restrict__ g2,
    const float* __restrict__ b2,
    float* __restrict__ out)
{
  const int b = blockIdx.x, t = threadIdx.x;

  __shared__ float4 s_MP4[480];             // 7680 B: M then P
  __shared__ float4 s_o4[NTOK+2];           // token state [0..3]
  __shared__ float  s_o1[NTOK+2];           // token state [4]
  __shared__ float4 s_w4[2][NH][NTOK+2];    // wp[0..3] per (jgroup,h,i)
  __shared__ float2 s_w2[2][NH][NTOK+2];    // {wp[4], ls}
  __shared__ float  s_cf[152];              // Wf | bf | g1 | b1 | g2 | b2
  __shared__ int    s_cidx[NTOK];
  __shared__ unsigned long long s_bal[2];

  const float* mpf = (const float*)s_MP4;
  float* mpw = (float*)s_MP4;

  // ---- fused precompute: M,P straight into LDS (600 entries) ----
  for (int idx = t; idx < 600; idx += BLK) {
    int which = idx / 300;
    int rem   = idx - which*300;
    int lh    = rem / 25;                   // l*NH + h, 0..11
    int ef    = rem - lh*25;
    int e = ef / 5, f = ef - (ef/5)*5;
    float acc = 0.f;
    if (which == 0) {
      const float* wq = Wq + lh*(DD*EDIM);
      const float* wk = Wk + lh*(DD*EDIM);
      #pragma unroll 8
      for (int d = 0; d < DD; ++d) acc += wq[d*5+e] * wk[d*5+f];
      acc *= 0.125f * 1.44269504088896340736f;   // fold log2(e) for exp2
    } else {
      int l = lh >> 2, h = lh & 3;
      const float* wv = Wv + lh*(DD*EDIM);
      const float* wo = Wo + (l*EDIM + f)*(NH*DD) + h*DD;   // contiguous d
      #pragma unroll 8
      for (int d = 0; d < DD; ++d) acc += wv[d*5+e] * wo[d];
    }
    mpw[which*960 + (lh*5 + e)*8 + f] = acc;
  }
  for (int r = t; r < 150; r += BLK) {
    float v;
    if      (r <  75) v = Wf[r];
    else if (r <  90) v = bfv[r-75];
    else if (r < 105) v = g1[r-90];
    else if (r < 120) v = b1[r-105];
    else if (r < 135) v = g2[r-120];
    else              v = b2[r-135];
    s_cf[r] = v;
  }

  // ---- setup: mask + ballot-based compaction ----
  float k0=0.f, k1=0.f, k2=0.f, msk=0.f;
  if (t < NTOK) {
    k0 = x[b*300 + 3*t];
    k1 = x[b*300 + 3*t + 1];
    k2 = x[b*300 + 3*t + 2];
    msk = (k2 > 0.f) ? 1.f : 0.f;
  }
  unsigned long long bal = __ballot(t < NTOK && msk != 0.f);
  if (t == 0)  s_bal[0] = bal;
  if (t == 64) s_bal[1] = bal;
  __syncthreads();                          // also covers mp/s_cf writes
  const unsigned long long bw0 = s_bal[0], bw1 = s_bal[1];
  // readfirstlane: nm (and all derived bounds) provably uniform
  const int nm = __builtin_amdgcn_readfirstlane(__popcll(bw0) + __popcll(bw1));
  if (t < NTOK) {
    int lane = t & 63;
    unsigned long long lm = (lane == 0) ? 0ull : ((1ull << lane) - 1ull);
    int pre = (t < 64) ? __popcll(bw0 & lm) : (__popcll(bw0) + __popcll(bw1 & lm));
    if (msk != 0.f) {
      s_o4[pre] = make_float4(k0, k1, k2, __sinf((float)t));
      s_o1[pre] = __cosf((float)t);
      s_cidx[t] = pre;
    } else {
      s_cidx[t] = nm;
    }
  }
  if (t == 0) {
    s_o4[nm]   = make_float4(0.f,0.f,0.f,0.f); s_o1[nm]   = 0.f;  // rep token
    s_o4[nm+1] = make_float4(0.f,0.f,0.f,0.f); s_o1[nm+1] = 0.f;
  }
  __syncthreads();

  // ---- static task mapping: 1 row/thread, adaptive j-split ----
  const int rowsN = nm + 1;                 // rows incl. rep token
  const int natt  = NH * rowsN;             // threads per j-group (<=404)
  const int nsplit = (2*natt <= BLK) ? 2 : 1;   // nm<=63 -> 2 (typical)
  const bool task = (t < natt*nsplit);
  int h = 0, i0 = 0, jlo = 0, jhi = 0;
  bool rep0 = false, corr = false;
  if (task) {
    int g  = t / natt;
    int tt = t - g*natt;
    h = tt / rowsN; i0 = tt - h*rowsN;
    rep0 = (i0 == nm);
    corr = (g == 0);                        // rep-correction applied once
    int jmid = nm >> 1;
    if (nsplit == 2) { jlo = g ? jmid : 0; jhi = g ? nm : jmid; }
    else             { jlo = 0; jhi = nm; }
  }
  const int wg = task ? (t / natt) : 0;
  const float wext = (float)(NTOK - nm);

  for (int l = 0; l < NL; ++l) {
    if (task) {
      // a = o @ M_h for this thread's row
      const float* Mh = mpf + ((l*NH + h)*EDIM)*8;
      float4 oA = s_o4[i0];  float oA4 = s_o1[i0];
      float oa[5] = {oA.x, oA.y, oA.z, oA.w, oA4};
      float a0[5];
      #pragma unroll
      for (int f = 0; f < 5; ++f) a0[f] = 0.f;
      #pragma unroll
      for (int e = 0; e < 5; ++e) {
        float4 mr = *(const float4*)(Mh + e*8); float m4 = Mh[e*8+4];
        float va = oa[e];
        a0[0] += va*mr.x; a0[1] += va*mr.y; a0[2] += va*mr.z;
        a0[3] += va*mr.w; a0[4] += va*m4;
      }
      if (rep0) { a0[0]=0.f; a0[1]=0.f; a0[2]=0.f; a0[3]=0.f; a0[4]=0.f; } // exp2(0)=1

      // attention j-loop: LDS broadcast reads, 1-row body, native exp2
      float ls0=0.f;
      float w00=0.f,w01=0.f,w02=0.f,w03=0.f,w04=0.f;
      #pragma unroll 8
      for (int j = jlo; j < jhi; ++j) {
        float4 oj = s_o4[j]; float oe = s_o1[j];
        float s0 = (a0[0]*oj.x + a0[1]*oj.y) + ((a0[2]*oj.z + a0[3]*oj.w) + a0[4]*oe);
        float p0 = fexp2(s0);
        ls0 += p0;
        w00 += p0*oj.x; w01 += p0*oj.y; w02 += p0*oj.z; w03 += p0*oj.w; w04 += p0*oe;
      }
      // rep row: uniform 1/100 row also averages (100-nm) masked tokens,
      // each carrying the rep state itself (applied once, in group 0).
      if (rep0 && corr) {
        w00 += wext*oa[0]; w01 += wext*oa[1]; w02 += wext*oa[2];
        w03 += wext*oa[3]; w04 += wext*oa[4];
      }

      // P-apply in the DENSE phase: wp = w @ P_h (unnormalized; ls carried)
      const float* Ph = mpf + 960 + ((l*NH + h)*EDIM)*8;
      float wr0[5] = {w00,w01,w02,w03,w04};
      float c00=0.f,c01=0.f,c02=0.f,c03=0.f,c04=0.f;
      #pragma unroll
      for (int e = 0; e < 5; ++e) {
        float4 pr = *(const float4*)(Ph + e*8); float p4 = Ph[e*8+4];
        float va = wr0[e];
        c00 += va*pr.x; c01 += va*pr.y; c02 += va*pr.z; c03 += va*pr.w; c04 += va*p4;
      }
      s_w4[wg][h][i0] = make_float4(c00, c01, c02, c03);
      s_w2[wg][h][i0] = make_float2(c04, ls0);
    }
    __syncthreads();

    // ---- token pass: merge pre-applied head outputs, LN1, FFN, LN2 ----
    if (t <= nm) {
      int i = t;
      bool rep = (i == nm);
      float4 ov = s_o4[i]; float ov4 = s_o1[i];
      float y[5] = {ov.x, ov.y, ov.z, ov.w, ov4};
      #pragma unroll
      for (int hh = 0; hh < NH; ++hh) {
        float4 wa = s_w4[0][hh][i]; float2 wb = s_w2[0][hh][i];
        float c0 = wa.x, c1 = wa.y, c2 = wa.z, c3 = wa.w, c4 = wb.x;
        float ls = wb.y;
        if (nsplit == 2) {
          float4 wa2 = s_w4[1][hh][i]; float2 wb2 = s_w2[1][hh][i];
          c0 += wa2.x; c1 += wa2.y; c2 += wa2.z; c3 += wa2.w; c4 += wb2.x;
          ls += wb2.y;
        }
        float inv = rep ? 0.01f : frcp(ls);
        y[0] += c0*inv; y[1] += c1*inv; y[2] += c2*inv; y[3] += c3*inv; y[4] += c4*inv;
      }
      float mu = 0.2f*(y[0]+y[1]+y[2]+y[3]+y[4]);
      float var = 0.f;
      #pragma unroll
      for (int e = 0; e < 5; ++e) { float d = y[e]-mu; var += d*d; }
      float iv = frsq(var*0.2f + 1e-5f);
      float l1[5];
      #pragma unroll
      for (int e = 0; e < 5; ++e)
        l1[e] = (y[e]-mu)*iv*s_cf[90+l*5+e] + s_cf[105+l*5+e];
      float r2[5];
      #pragma unroll
      for (int e = 0; e < 5; ++e) {
        float acc = s_cf[75+l*5+e];
        #pragma unroll
        for (int f = 0; f < 5; ++f) acc += l1[f]*s_cf[l*25+e*5+f];
        acc = acc > 0.f ? acc : 0.f;
        r2[e] = acc + l1[e];
      }
      float mu2 = 0.2f*(r2[0]+r2[1]+r2[2]+r2[3]+r2[4]);
      float var2 = 0.f;
      #pragma unroll
      for (int e = 0; e < 5; ++e) { float d = r2[e]-mu2; var2 += d*d; }
      float iv2 = frsq(var2*0.2f + 1e-5f);
      float no0 = (r2[0]-mu2)*iv2*s_cf[120+l*5+0] + s_cf[135+l*5+0];
      float no1 = (r2[1]-mu2)*iv2*s_cf[120+l*5+1] + s_cf[135+l*5+1];
      float no2 = (r2[2]-mu2)*iv2*s_cf[120+l*5+2] + s_cf[135+l*5+2];
      float no3 = (r2[3]-mu2)*iv2*s_cf[120+l*5+3] + s_cf[135+l*5+3];
      float no4 = (r2[4]-mu2)*iv2*s_cf[120+l*5+4] + s_cf[135+l*5+4];
      s_o4[i] = make_float4(no0, no1, no2, no3);
      s_o1[i] = no4;
    }
    __syncthreads();
  }

  // ---- expand compacted state back to [N, E] ----
  for (int r = t; r < NTOK*EDIM; r += BLK) {
    int i = r / EDIM;
    int e = r - i*EDIM;
    int c = s_cidx[i];
    float v = (e < 4) ? ((const float*)&s_o4[c])[e] : s_o1[c];
    out[b*(NTOK*EDIM) + r] = v;
  }
}

extern "C" void kernel_launch(void* const* d_in, const int* in_sizes, int n_in,
                              void* d_out, int out_size, void* d_ws, size_t ws_size,
                              hipStream_t stream) {
  const float* x  = (const float*)d_in[0];
  const float* Wq = (const float*)d_in[1];
  const float* Wk = (const float*)d_in[2];
  const float* Wv = (const float*)d_in[3];
  const float* Wo = (const float*)d_in[4];
  const float* Wf = (const float*)d_in[5];
  const float* bf = (const float*)d_in[6];
  const float* g1 = (const float*)d_in[7];
  const float* b1 = (const float*)d_in[8];
  const float* g2 = (const float*)d_in[9];
  const float* b2 = (const float*)d_in[10];
  float* outp = (float*)d_out;

  encoder_kernel<<<1024, BLK, 0, stream>>>(x, Wq, Wk, Wv, Wo,
                                           Wf, bf, g1, b1, g2, b2, outp);
}